// Round 7
// baseline (354.054 us; speedup 1.0000x reference)
//
#include <hip/hip_runtime.h>

#define NFEAT 256
#define HID 64
#define NCLASS 40
#define BCAP 8192       // per-bucket capacity (csr words per 512-node bucket)

typedef _Float16 half8 __attribute__((ext_vector_type(8)));
typedef float floatx4 __attribute__((ext_vector_type(4)));

// ---------- wave/block inclusive scan ----------
__device__ __forceinline__ int wave_iscan(int v, int lane) {
    #pragma unroll
    for (int o = 1; o < 64; o <<= 1) {
        int u = __shfl_up(v, o, 64);
        if (lane >= o) v += u;
    }
    return v;
}

template<int NT>
__device__ __forceinline__ int block_iscan(int v, int t, int* wsum) {
    const int NW = NT / 64;
    int lane = t & 63, wv = t >> 6;
    int s = wave_iscan(v, lane);
    if (lane == 63) wsum[wv] = s;
    __syncthreads();
    if (wv == 0) {
        int w = (lane < NW) ? wsum[lane] : 0;
        #pragma unroll
        for (int o = 1; o < NW; o <<= 1) {
            int u = __shfl_up(w, o, 64);
            if (lane >= o) w += u;
        }
        if (lane < NW) wsum[lane] = w;
    }
    __syncthreads();
    int add = (wv > 0) ? wsum[wv - 1] : 0;
    return s + add;
}

// ---------- phase 1: per-node degree count (global atomics) + W1..3 fp16^T convert ----------
__global__ __launch_bounds__(256) void k_deg(const int* __restrict__ dst, int* __restrict__ deg,
                                             int E, int ndeg,
                                             const float* __restrict__ W1, const float* __restrict__ W2,
                                             const float* __restrict__ W3, _Float16* __restrict__ Wt16) {
    int t = threadIdx.x;
    int bid = blockIdx.x;
    if (bid >= ndeg) {
        int l = bid - ndeg;
        const float* Ws = (l == 0) ? W1 : (l == 1) ? W2 : W3;
        _Float16* wt = Wt16 + l * 4096;
        for (int i = t; i < 4096; i += 256) {
            int col = i >> 6, k = i & 63;
            wt[i] = (_Float16)Ws[k * HID + col];
        }
        return;
    }
    int stride = ndeg * 256;
    for (int i = bid * 256 + t; i < E; i += stride)
        atomicAdd(&deg[dst[i]], 1);
}

// ---------- phase 2: per-bucket offset scan -> pk/dinv (196 tiny blocks) ----------
__global__ __launch_bounds__(512) void k_off(const int* __restrict__ deg, unsigned* __restrict__ pk,
                                             float* __restrict__ dinv, int N) {
    __shared__ int wsum[8];
    int t = threadIdx.x;
    int b = blockIdx.x;
    int node = (b << 9) + t;
    int v = (node < N) ? deg[node] : 0;
    int incl = block_iscan<512>(v, t, wsum);
    int excl = incl - v;
    if (node < N) {
        int c = v > 2047 ? 2047 : v;
        if (excl >= BCAP) c = 0;
        else if (excl + c > BCAP) c = BCAP - excl;
        pk[node] = (unsigned)(b * BCAP + excl) | ((unsigned)c << 21);
        dinv[node] = rsqrtf((float)c + 1.0f);
    }
}

// ---------- phase 3 fused: CSR fill via atomic scatter (blocks < nfill) + h0 GEMM ----------
__global__ __launch_bounds__(256) void k_fill(const int* __restrict__ src, const int* __restrict__ dst,
                                              const unsigned* __restrict__ pk, int* __restrict__ cnt,
                                              int* __restrict__ csr, int E, int nfill,
                                              const float* __restrict__ x, const float* __restrict__ Wx,
                                              const float* __restrict__ bx, _Float16* __restrict__ h0,
                                              int N, int ngemm) {
    __shared__ _Float16 Wt[64][264];   // used by gemm blocks only (33.8 KB)
    int t = threadIdx.x;
    int bid = blockIdx.x;

    if (bid >= nfill) {
        // ---- h0 = relu(x @ Wx + bx) ----
        {
            int c = t & 63, k0 = (t >> 6) * 64;
            for (int k = k0; k < k0 + 64; ++k)
                Wt[c][k] = (_Float16)Wx[k * HID + c];
        }
        __syncthreads();
        int lane = t & 63, wv = t >> 6;
        int lg = lane >> 4, ln = lane & 15;
        int wid = (bid - nfill) * 4 + wv;
        int nw = ngemm * 4;
        float bb[4];
        #pragma unroll
        for (int g = 0; g < 4; ++g) bb[g] = bx[g * 16 + ln];
        int ntiles = N >> 4;
        for (int tile = wid; tile < ntiles; tile += nw) {
            int row0 = tile << 4;
            const float* xr = x + (size_t)(row0 + ln) * NFEAT + lg * 8;
            float4 av[16];
            #pragma unroll
            for (int ks = 0; ks < 8; ++ks) {
                av[2 * ks]     = *(const float4*)(xr + ks * 32);
                av[2 * ks + 1] = *(const float4*)(xr + ks * 32 + 4);
            }
            floatx4 acc[4] = {{0.f,0.f,0.f,0.f},{0.f,0.f,0.f,0.f},{0.f,0.f,0.f,0.f},{0.f,0.f,0.f,0.f}};
            #pragma unroll
            for (int ks = 0; ks < 8; ++ks) {
                float4 a0 = av[2 * ks], a1 = av[2 * ks + 1];
                half8 a;
                a[0]=(_Float16)a0.x; a[1]=(_Float16)a0.y; a[2]=(_Float16)a0.z; a[3]=(_Float16)a0.w;
                a[4]=(_Float16)a1.x; a[5]=(_Float16)a1.y; a[6]=(_Float16)a1.z; a[7]=(_Float16)a1.w;
                #pragma unroll
                for (int g = 0; g < 4; ++g) {
                    half8 b = *(const half8*)&Wt[g * 16 + ln][ks * 32 + lg * 8];
                    acc[g] = __builtin_amdgcn_mfma_f32_16x16x32_f16(a, b, acc[g], 0, 0, 0);
                }
            }
            #pragma unroll
            for (int g = 0; g < 4; ++g) {
                #pragma unroll
                for (int r = 0; r < 4; ++r) {
                    int row = row0 + lg * 4 + r;
                    h0[(size_t)row * HID + g * 16 + ln] = (_Float16)fmaxf(acc[g][r] + bb[g], 0.f);
                }
            }
        }
        return;
    }

    // ---- CSR fill: one atomic + one 4B write per edge ----
    int stride = nfill * 256;
    for (int i = bid * 256 + t; i < E; i += stride) {
        int d = dst[i], s = src[i];
        unsigned p = pk[d];
        int idx = atomicAdd(&cnt[d], 1);
        if (idx < (int)(p >> 21))
            csr[(p & 0x1FFFFFu) + idx] = s;
    }
}

// ---------- fused GCN layer: z = A·h (gather+self), then out = z@W + b via MFMA ----------
// block = 256 thr = 4 waves = 32 nodes; wave = 8 subgroups x 8 lanes (sg owns node, f8 owns
// 16B feature seg). VGPR gathers; next chunk's csr/norm prefetched during consume.
template<int WRN>
__global__ __launch_bounds__(256) void k_layer(const _Float16* __restrict__ Ph, const int* __restrict__ csr,
                                               const unsigned* __restrict__ pk, const float* __restrict__ dinv,
                                               const _Float16* __restrict__ Wt, const float* __restrict__ b,
                                               float* __restrict__ normf,
                                               _Float16* __restrict__ Lout, int N) {
    __shared__ _Float16 z[32][72];     // aggregated features
    __shared__ _Float16 ot[32][72];    // output tile
    int t = threadIdx.x;
    int lane = t & 63, wv = t >> 6;
    int sg = lane >> 3, f8 = lane & 7;
    int lg = lane >> 4, ln = lane & 15;
    int nb = blockIdx.x << 5;
    int node = nb + wv * 8 + sg;
    bool valid = node < N;
    int nodec = valid ? node : (N - 1);
    int col = wv * 16 + ln;
    half8 bf0 = *(const half8*)(Wt + col * 64 + lg * 8);
    half8 bf1 = *(const half8*)(Wt + col * 64 + 32 + lg * 8);
    float bb = b[col];

    unsigned pkv = valid ? pk[node] : 0u;
    int off = (int)(pkv & 0x1FFFFFu);
    int c = valid ? (int)(pkv >> 21) : 0;
    float dd = valid ? dinv[node] : 0.f;
    const _Float16* pb = Ph + f8 * 8;
    float acc[8];
    {
        half8 self = *(const half8*)(pb + (size_t)nodec * HID);
        float dd2 = dd * dd;
        #pragma unroll
        for (int j = 0; j < 8; ++j) acc[j] = (float)self[j] * dd2;
    }
    int ecur = f8;
    bool ok = ecur < c;
    int s_cur = ok ? csr[off + ecur] : nodec;
    float nm_cur;
    if (WRN) {
        nm_cur = ok ? dinv[s_cur] * dd : 0.f;
        if (ok) normf[off + ecur] = nm_cur;
    } else {
        nm_cur = ok ? normf[off + ecur] : 0.f;
    }
    for (int jj = 0; jj < c; jj += 8) {
        int en = jj + 8 + f8;
        bool okn = en < c;
        int s_nxt = okn ? csr[off + en] : nodec;
        float nm_nxt;
        if (WRN) {
            nm_nxt = okn ? dinv[s_nxt] * dd : 0.f;
            if (okn) normf[off + en] = nm_nxt;
        } else {
            nm_nxt = okn ? normf[off + en] : 0.f;
        }
        #pragma unroll
        for (int j = 0; j < 8; ++j) {
            int ss = __shfl(s_cur, j, 8);
            float nn = __shfl(nm_cur, j, 8);
            half8 v = *(const half8*)(pb + (size_t)ss * HID);
            #pragma unroll
            for (int q = 0; q < 8; ++q) acc[q] = fmaf((float)v[q], nn, acc[q]);
        }
        s_cur = s_nxt; nm_cur = nm_nxt;
    }
    {
        half8 zv;
        #pragma unroll
        for (int j = 0; j < 8; ++j) zv[j] = (_Float16)acc[j];
        *(half8*)&z[wv * 8 + sg][f8 * 8] = zv;
    }
    __syncthreads();
    floatx4 acc0 = {0.f, 0.f, 0.f, 0.f}, acc1 = {0.f, 0.f, 0.f, 0.f};
    {
        half8 a0 = *(const half8*)&z[ln][lg * 8];
        half8 a1 = *(const half8*)&z[16 + ln][lg * 8];
        acc0 = __builtin_amdgcn_mfma_f32_16x16x32_f16(a0, bf0, acc0, 0, 0, 0);
        acc1 = __builtin_amdgcn_mfma_f32_16x16x32_f16(a1, bf0, acc1, 0, 0, 0);
        a0 = *(const half8*)&z[ln][32 + lg * 8];
        a1 = *(const half8*)&z[16 + ln][32 + lg * 8];
        acc0 = __builtin_amdgcn_mfma_f32_16x16x32_f16(a0, bf1, acc0, 0, 0, 0);
        acc1 = __builtin_amdgcn_mfma_f32_16x16x32_f16(a1, bf1, acc1, 0, 0, 0);
    }
    #pragma unroll
    for (int r = 0; r < 4; ++r) {
        ot[lg * 4 + r][wv * 16 + ln] = (_Float16)(acc0[r] + bb);
        ot[16 + lg * 4 + r][wv * 16 + ln] = (_Float16)(acc1[r] + bb);
    }
    __syncthreads();
    {
        int row = t >> 3, c8 = t & 7;
        int onode = nb + row;
        if (onode < N)
            *(half8*)(Lout + (size_t)onode * HID + c8 * 8) = *(const half8*)&ot[row][c8 * 8];
    }
}

// ---------- out = relu(((L1+L2+L3)/3) @ Wz + bz) ----------
__global__ __launch_bounds__(256) void k_gemm_out(const _Float16* __restrict__ L1, const _Float16* __restrict__ L2,
                                                  const _Float16* __restrict__ L3, const float* __restrict__ Wz,
                                                  const float* __restrict__ bz, float* __restrict__ outp, int N) {
    int t = threadIdx.x;
    int lane = t & 63, lg = lane >> 4, ln = lane & 15;
    int wid = (blockIdx.x * 256 + t) >> 6;
    int nw = (gridDim.x * 256) >> 6;
    half8 b[2][3];
    float bb[3];
    #pragma unroll
    for (int g = 0; g < 3; ++g) {
        int col = g * 16 + ln;
        bb[g] = (col < NCLASS) ? bz[col] : 0.f;
        #pragma unroll
        for (int ks = 0; ks < 2; ++ks)
            #pragma unroll
            for (int j = 0; j < 8; ++j)
                b[ks][g][j] = (col < NCLASS) ? (_Float16)(Wz[(ks * 32 + lg * 8 + j) * NCLASS + col] * (1.f / 3.f)) : (_Float16)0.f;
    }
    int ntiles = N >> 4;
    for (int tile = wid; tile < ntiles; tile += nw) {
        int row0 = tile << 4;
        size_t rb = (size_t)(row0 + ln) * HID + lg * 8;
        floatx4 acc[3] = {{0.f,0.f,0.f,0.f},{0.f,0.f,0.f,0.f},{0.f,0.f,0.f,0.f}};
        #pragma unroll
        for (int ks = 0; ks < 2; ++ks) {
            half8 a1 = *(const half8*)(L1 + rb + ks * 32);
            half8 a2 = *(const half8*)(L2 + rb + ks * 32);
            half8 a3 = *(const half8*)(L3 + rb + ks * 32);
            half8 a;
            #pragma unroll
            for (int j = 0; j < 8; ++j)
                a[j] = (_Float16)((float)a1[j] + (float)a2[j] + (float)a3[j]);
            #pragma unroll
            for (int g = 0; g < 3; ++g)
                acc[g] = __builtin_amdgcn_mfma_f32_16x16x32_f16(a, b[ks][g], acc[g], 0, 0, 0);
        }
        #pragma unroll
        for (int g = 0; g < 3; ++g) {
            int col = g * 16 + ln;
            if (col < NCLASS) {
                #pragma unroll
                for (int r = 0; r < 4; ++r)
                    outp[(size_t)(row0 + lg * 4 + r) * NCLASS + col] = fmaxf(acc[g][r] + bb[g], 0.f);
            }
        }
    }
}

extern "C" void kernel_launch(void* const* d_in, const int* in_sizes, int n_in,
                              void* d_out, int out_size, void* d_ws, size_t ws_size,
                              hipStream_t stream) {
    const float* x  = (const float*)d_in[0];
    const int*   ei = (const int*)d_in[1];
    const float* Wx = (const float*)d_in[2];
    const float* bx = (const float*)d_in[3];
    const float* W1 = (const float*)d_in[4];
    const float* b1 = (const float*)d_in[5];
    const float* W2 = (const float*)d_in[6];
    const float* b2 = (const float*)d_in[7];
    const float* W3 = (const float*)d_in[8];
    const float* b3 = (const float*)d_in[9];
    const float* Wz = (const float*)d_in[10];
    const float* bz = (const float*)d_in[11];
    float* out = (float*)d_out;

    int N = in_sizes[0] / NFEAT;
    int E = in_sizes[1] / 2;
    const int* src = ei;
    const int* dst = ei + E;
    int nbuckets = (N + 511) >> 9;   // 196 for N=100000

    size_t nh = (size_t)N * HID;
    size_t Npad = ((size_t)N + 7) / 8 * 8;
    // 4B-unit layout: deg | cnt | dinv | pk | H0 | L1 | L2 | L3 | csr | Wt16 | normf
    int*      deg  = (int*)d_ws;
    int*      cnt  = deg + Npad;
    float*    dinv = (float*)(cnt + Npad);
    unsigned* pk   = (unsigned*)(dinv + Npad);
    _Float16* H0   = (_Float16*)(pk + Npad);
    _Float16* L1   = H0 + nh;
    _Float16* L2   = L1 + nh;
    _Float16* L3   = L2 + nh;
    int*      csr  = (int*)(L3 + nh);
    _Float16* Wt16 = (_Float16*)(csr + (size_t)nbuckets * BCAP);
    float*    normf = (float*)(Wt16 + 3 * 4096);

    int ndeg = 1024, nfill = 1024, ngemm = 512;
    hipMemsetAsync(deg, 0, 2 * Npad * sizeof(int), stream);
    k_deg<<<ndeg + 3, 256, 0, stream>>>(dst, deg, E, ndeg, W1, W2, W3, Wt16);
    k_off<<<nbuckets, 512, 0, stream>>>(deg, pk, dinv, N);
    k_fill<<<nfill + ngemm, 256, 0, stream>>>(src, dst, pk, cnt, csr, E, nfill,
                                              x, Wx, bx, H0, N, ngemm);

    int layer_blocks = (N + 31) / 32;
    k_layer<1><<<layer_blocks, 256, 0, stream>>>(H0, csr, pk, dinv, Wt16,          b1, normf, L1, N);
    k_layer<0><<<layer_blocks, 256, 0, stream>>>(L1, csr, pk, dinv, Wt16 + 4096,   b2, normf, L2, N);
    k_layer<0><<<layer_blocks, 256, 0, stream>>>(L2, csr, pk, dinv, Wt16 + 8192,   b3, normf, L3, N);

    k_gemm_out<<<512, 256, 0, stream>>>(L1, L2, L3, Wz, bz, out, N);
}

// Round 8
// 322.317 us; speedup vs baseline: 1.0985x; 1.0985x over previous
//
#include <hip/hip_runtime.h>

#define NFEAT 256
#define HID 64
#define NCLASS 40
#define EPB 4096        // edges per binning block
#define BCAP 8192       // per-bucket capacity (words / csr entries)

typedef _Float16 half8 __attribute__((ext_vector_type(8)));
typedef float floatx4 __attribute__((ext_vector_type(4)));

// ---------- wave/block inclusive scans (2 barriers instead of 16-18) ----------
__device__ __forceinline__ int wave_iscan(int v, int lane) {
    #pragma unroll
    for (int o = 1; o < 64; o <<= 1) {
        int u = __shfl_up(v, o, 64);
        if (lane >= o) v += u;
    }
    return v;
}

template<int NT>
__device__ __forceinline__ int block_iscan(int v, int t, int* wsum) {
    const int NW = NT / 64;
    int lane = t & 63, wv = t >> 6;
    int s = wave_iscan(v, lane);
    if (lane == 63) wsum[wv] = s;
    __syncthreads();
    if (wv == 0) {
        int w = (lane < NW) ? wsum[lane] : 0;
        #pragma unroll
        for (int o = 1; o < NW; o <<= 1) {
            int u = __shfl_up(w, o, 64);
            if (lane >= o) w += u;
        }
        if (lane < NW) wsum[lane] = w;
    }
    __syncthreads();
    int add = (wv > 0) ? wsum[wv - 1] : 0;
    return s + add;
}

struct BinSM {
    int lcnt[256], loff[256], lcur[256], gbase[256], wsum[4];
    int sdst[EPB];
    int words[EPB];
};

// ---------- fused preprocessing: edge binning + W1..3 fp16^T convert + h0 GEMM ----------
__global__ __launch_bounds__(256) void k_pre(const int* __restrict__ src, const int* __restrict__ dst,
                                             int* __restrict__ bcur, int* __restrict__ bwords,
                                             int nbuckets, int E, int nbin,
                                             const float* __restrict__ W1, const float* __restrict__ W2,
                                             const float* __restrict__ W3, _Float16* __restrict__ Wt16,
                                             const float* __restrict__ x, const float* __restrict__ Wx,
                                             const float* __restrict__ bx, _Float16* __restrict__ h0,
                                             int N, int ngemm) {
    __shared__ __align__(16) char smraw[sizeof(BinSM)];
    int t = threadIdx.x;
    int bid = blockIdx.x;

    if (bid >= nbin && bid < nbin + 3) {
        int l = bid - nbin;
        const float* Ws = (l == 0) ? W1 : (l == 1) ? W2 : W3;
        _Float16* wt = Wt16 + l * 4096;
        for (int i = t; i < 4096; i += 256) {
            int col = i >> 6, k = i & 63;
            wt[i] = (_Float16)Ws[k * HID + col];
        }
        return;
    }

    if (bid >= nbin + 3) {
        // ---- h0 GEMM part ----
        _Float16 (*Wt)[264] = (_Float16 (*)[264])smraw;   // 64 x 264 fp16 = 33.8 KB
        {
            int c = t & 63, k0 = (t >> 6) * 64;
            for (int k = k0; k < k0 + 64; ++k)
                Wt[c][k] = (_Float16)Wx[k * HID + c];
        }
        __syncthreads();
        int lane = t & 63, wv = t >> 6;
        int lg = lane >> 4, ln = lane & 15;
        int gb = bid - nbin - 3;
        int wid = gb * 4 + wv;
        int nw = ngemm * 4;
        float bb[4];
        #pragma unroll
        for (int g = 0; g < 4; ++g) bb[g] = bx[g * 16 + ln];
        int ntiles = N >> 4;
        for (int tile = wid; tile < ntiles; tile += nw) {
            int row0 = tile << 4;
            const float* xr = x + (size_t)(row0 + ln) * NFEAT + lg * 8;
            float4 av[16];
            #pragma unroll
            for (int ks = 0; ks < 8; ++ks) {
                av[2 * ks]     = *(const float4*)(xr + ks * 32);
                av[2 * ks + 1] = *(const float4*)(xr + ks * 32 + 4);
            }
            floatx4 acc[4] = {{0.f,0.f,0.f,0.f},{0.f,0.f,0.f,0.f},{0.f,0.f,0.f,0.f},{0.f,0.f,0.f,0.f}};
            #pragma unroll
            for (int ks = 0; ks < 8; ++ks) {
                float4 a0 = av[2 * ks], a1 = av[2 * ks + 1];
                half8 a;
                a[0]=(_Float16)a0.x; a[1]=(_Float16)a0.y; a[2]=(_Float16)a0.z; a[3]=(_Float16)a0.w;
                a[4]=(_Float16)a1.x; a[5]=(_Float16)a1.y; a[6]=(_Float16)a1.z; a[7]=(_Float16)a1.w;
                #pragma unroll
                for (int g = 0; g < 4; ++g) {
                    half8 b = *(const half8*)&Wt[g * 16 + ln][ks * 32 + lg * 8];
                    acc[g] = __builtin_amdgcn_mfma_f32_16x16x32_f16(a, b, acc[g], 0, 0, 0);
                }
            }
            #pragma unroll
            for (int g = 0; g < 4; ++g) {
                #pragma unroll
                for (int r = 0; r < 4; ++r) {
                    int row = row0 + lg * 4 + r;
                    h0[(size_t)row * HID + g * 16 + ln] = (_Float16)fmaxf(acc[g][r] + bb[g], 0.f);
                }
            }
        }
        return;
    }

    // ---- binning part ----
    BinSM* sm = (BinSM*)smraw;
    int base = bid * EPB;
    int n = E - base; if (n > EPB) n = EPB;
    sm->lcnt[t] = 0;
    __syncthreads();
    for (int i = t; i < n; i += 256) {
        int d = dst[base + i];
        sm->sdst[i] = d;
        atomicAdd(&sm->lcnt[d >> 9], 1);
    }
    __syncthreads();
    int v = sm->lcnt[t];
    int incl = block_iscan<256>(v, t, sm->wsum);
    int excl = incl - v;
    sm->loff[t] = excl; sm->lcur[t] = excl;
    __syncthreads();
    for (int i = t; i < n; i += 256) {
        int d = sm->sdst[i], s = src[base + i];
        int b = d >> 9;
        int p = atomicAdd(&sm->lcur[b], 1);
        sm->words[p] = s | ((d & 511) << 17);     // s < 2^17
    }
    __syncthreads();
    if (t < nbuckets) {
        int c = sm->lcnt[t];
        sm->gbase[t] = c > 0 ? atomicAdd(&bcur[t], c) : 0;
    }
    __syncthreads();
    int lane = t & 63, wv = t >> 6;
    for (int b = wv; b < nbuckets; b += 4) {
        int o = sm->loff[b], c = sm->lcnt[b], gb = sm->gbase[b];
        int* dstp = bwords + (size_t)b * BCAP;
        for (int i = lane; i < c; i += 64) {
            int gp = gb + i;
            if (gp < BCAP) dstp[gp] = sm->words[o + i];
        }
    }
}

// ---------- phase 2: per-bucket CSR build + pk/dinv ----------
__global__ __launch_bounds__(256) void k_csr(const int* __restrict__ bcur, const int* __restrict__ bwords,
                                             int* __restrict__ csr, unsigned* __restrict__ pk,
                                             float* __restrict__ dinv, int N) {
    __shared__ int cnt[512], cur[512], wsum[4];
    __shared__ int lcsr[BCAP];     // 32 KB
    int t = threadIdx.x;
    int b = blockIdx.x;
    int nodebase = b << 9;
    int nb = bcur[b]; if (nb > BCAP) nb = BCAP;
    cnt[t] = 0; cnt[t + 256] = 0;
    __syncthreads();
    const int* wp = bwords + (size_t)b * BCAP;
    for (int i = t; i < nb; i += 256)
        atomicAdd(&cnt[wp[i] >> 17], 1);
    __syncthreads();
    int v0 = cnt[2 * t], v1 = cnt[2 * t + 1];
    int p = v0 + v1;
    int incl = block_iscan<256>(p, t, wsum);
    int e = incl - p;
    cur[2 * t] = e; cur[2 * t + 1] = e + v0;
    #pragma unroll
    for (int j = 0; j < 2; ++j) {
        int node = nodebase + 2 * t + j;
        if (node < N) {
            int c = cnt[2 * t + j]; if (c > 2047) c = 2047;
            pk[node] = (unsigned)(b * BCAP + cur[2 * t + j]) | ((unsigned)c << 21);
            dinv[node] = rsqrtf((float)c + 1.0f);
        }
    }
    __syncthreads();
    for (int i = t; i < nb; i += 256) {
        int w = wp[i];
        int pos = atomicAdd(&cur[w >> 17], 1);
        lcsr[pos] = w & 0x1FFFF;
    }
    __syncthreads();
    int* cp = csr + (size_t)b * BCAP;
    for (int i = t; i < nb; i += 256) cp[i] = lcsr[i];
}

// ---------- fused GCN layer with 2-stage register pipeline ----------
// block = 256 thr = 4 waves = 32 nodes; wave = 8 subgroups x 8 lanes (sg owns node, f8 owns
// 16B feature seg). While consuming chunk k's rows (RA), issue chunk k+1's rows (RB) and load
// chunk k+2's csr/norm — row-load latency hides under the FMA consume.
// FUSE=1 (layer 3): skip Lout store; out = relu(((L1+L2+ot)/3) @ Wz + bz), linear rows.
template<int WRN, int FUSE>
__global__ __launch_bounds__(256) void k_layer(const _Float16* __restrict__ Ph, const int* __restrict__ csr,
                                               const unsigned* __restrict__ pk, const float* __restrict__ dinv,
                                               const _Float16* __restrict__ Wt, const float* __restrict__ b,
                                               float* __restrict__ normf,
                                               _Float16* __restrict__ Lout, int N,
                                               const _Float16* __restrict__ L1p, const _Float16* __restrict__ L2p,
                                               const float* __restrict__ Wz, const float* __restrict__ bz,
                                               float* __restrict__ outp) {
    __shared__ _Float16 z[32][72];     // aggregated features / (FUSE) averaged A
    __shared__ _Float16 ot[32][72];    // layer output tile
    __shared__ float oout[FUSE ? 32 : 1][FUSE ? 48 : 1];   // FUSE: final out tile
    int t = threadIdx.x;
    int lane = t & 63, wv = t >> 6;
    int sg = lane >> 3, f8 = lane & 7;
    int lg = lane >> 4, ln = lane & 15;
    int nb = blockIdx.x << 5;
    int node = nb + wv * 8 + sg;
    bool valid = node < N;
    int nodec = valid ? node : (N - 1);
    int col = wv * 16 + ln;
    half8 bf0 = *(const half8*)(Wt + col * 64 + lg * 8);
    half8 bf1 = *(const half8*)(Wt + col * 64 + 32 + lg * 8);
    float bb = b[col];

    unsigned pkv = valid ? pk[node] : 0u;
    int off = (int)(pkv & 0x1FFFFFu);
    int c = valid ? (int)(pkv >> 21) : 0;
    float dd = valid ? dinv[node] : 0.f;
    const _Float16* pb = Ph + f8 * 8;
    float acc[8];
    {
        half8 self = *(const half8*)(pb + (size_t)nodec * HID);
        float dd2 = dd * dd;
        #pragma unroll
        for (int j = 0; j < 8; ++j) acc[j] = (float)self[j] * dd2;
    }
    // ---- pipeline prologue: chunk0 (A) and chunk1 (B) edge data; issue chunk0 rows ----
    half8 RA[8], RB[8];
    int eA0 = f8, eB0 = 8 + f8;
    bool okA = eA0 < c, okB = eB0 < c;
    int sA = okA ? csr[off + eA0] : nodec;
    int sB = okB ? csr[off + eB0] : nodec;
    float nmA, nmB;
    if (WRN) {
        nmA = okA ? dinv[sA] * dd : 0.f; if (okA) normf[off + eA0] = nmA;
        nmB = okB ? dinv[sB] * dd : 0.f; if (okB) normf[off + eB0] = nmB;
    } else {
        nmA = okA ? normf[off + eA0] : 0.f;
        nmB = okB ? normf[off + eB0] : 0.f;
    }
    #pragma unroll
    for (int j = 0; j < 8; ++j) {
        int ss = __shfl(sA, j, 8);
        RA[j] = *(const half8*)(pb + (size_t)ss * HID);
    }
    for (int jj = 0; jj < c; jj += 16) {
        // --- phase A: issue RB rows; load chunk jj+16 (A-slot); consume RA ---
        #pragma unroll
        for (int j = 0; j < 8; ++j) {
            int ss = __shfl(sB, j, 8);
            RB[j] = *(const half8*)(pb + (size_t)ss * HID);
        }
        {
            int e2 = jj + 16 + f8;
            bool ok2 = e2 < c;
            int s2 = ok2 ? csr[off + e2] : nodec;
            float nm2;
            if (WRN) { nm2 = ok2 ? dinv[s2] * dd : 0.f; if (ok2) normf[off + e2] = nm2; }
            else nm2 = ok2 ? normf[off + e2] : 0.f;
            #pragma unroll
            for (int j = 0; j < 8; ++j) {
                float nn = __shfl(nmA, j, 8);
                #pragma unroll
                for (int q = 0; q < 8; ++q) acc[q] = fmaf((float)RA[j][q], nn, acc[q]);
            }
            sA = s2; nmA = nm2;
        }
        if (jj + 8 >= c) break;
        // --- phase B: issue RA rows (new A = chunk jj+16); load chunk jj+24 (B-slot); consume RB ---
        #pragma unroll
        for (int j = 0; j < 8; ++j) {
            int ss = __shfl(sA, j, 8);
            RA[j] = *(const half8*)(pb + (size_t)ss * HID);
        }
        {
            int e2 = jj + 24 + f8;
            bool ok2 = e2 < c;
            int s2 = ok2 ? csr[off + e2] : nodec;
            float nm2;
            if (WRN) { nm2 = ok2 ? dinv[s2] * dd : 0.f; if (ok2) normf[off + e2] = nm2; }
            else nm2 = ok2 ? normf[off + e2] : 0.f;
            #pragma unroll
            for (int j = 0; j < 8; ++j) {
                float nn = __shfl(nmB, j, 8);
                #pragma unroll
                for (int q = 0; q < 8; ++q) acc[q] = fmaf((float)RB[j][q], nn, acc[q]);
            }
            sB = s2; nmB = nm2;
        }
    }
    {
        half8 zv;
        #pragma unroll
        for (int j = 0; j < 8; ++j) zv[j] = (_Float16)acc[j];
        *(half8*)&z[wv * 8 + sg][f8 * 8] = zv;
    }
    __syncthreads();
    // MFMA: two 16-row tiles; ot[rows][wv*16 .. +15] = z @ W + b
    floatx4 acc0 = {0.f, 0.f, 0.f, 0.f}, acc1 = {0.f, 0.f, 0.f, 0.f};
    {
        half8 a0 = *(const half8*)&z[ln][lg * 8];
        half8 a1 = *(const half8*)&z[16 + ln][lg * 8];
        acc0 = __builtin_amdgcn_mfma_f32_16x16x32_f16(a0, bf0, acc0, 0, 0, 0);
        acc1 = __builtin_amdgcn_mfma_f32_16x16x32_f16(a1, bf0, acc1, 0, 0, 0);
        a0 = *(const half8*)&z[ln][32 + lg * 8];
        a1 = *(const half8*)&z[16 + ln][32 + lg * 8];
        acc0 = __builtin_amdgcn_mfma_f32_16x16x32_f16(a0, bf1, acc0, 0, 0, 0);
        acc1 = __builtin_amdgcn_mfma_f32_16x16x32_f16(a1, bf1, acc1, 0, 0, 0);
    }
    #pragma unroll
    for (int r = 0; r < 4; ++r) {
        ot[lg * 4 + r][wv * 16 + ln] = (_Float16)(acc0[r] + bb);
        ot[16 + lg * 4 + r][wv * 16 + ln] = (_Float16)(acc1[r] + bb);
    }
    __syncthreads();

    if (!FUSE) {
        // coalesced store of the 32x64 fp16 tile
        int row = t >> 3, c8 = t & 7;
        int onode = nb + row;
        if (onode < N)
            *(half8*)(Lout + (size_t)onode * HID + c8 * 8) = *(const half8*)&ot[row][c8 * 8];
    } else {
        // ---- fused output epilogue (linear rows) ----
        {
            int row = t >> 3, c8 = t & 7;
            int onode = nb + row;
            half8 a1, a2;
            if (onode < N) {
                a1 = *(const half8*)(L1p + (size_t)onode * HID + c8 * 8);
                a2 = *(const half8*)(L2p + (size_t)onode * HID + c8 * 8);
            } else {
                #pragma unroll
                for (int j = 0; j < 8; ++j) { a1[j] = (_Float16)0.f; a2[j] = (_Float16)0.f; }
            }
            half8 l3 = *(const half8*)&ot[row][c8 * 8];
            half8 s;
            #pragma unroll
            for (int j = 0; j < 8; ++j)
                s[j] = (_Float16)(((float)a1[j] + (float)a2[j] + (float)l3[j]) * (1.f / 3.f));
            *(half8*)&z[row][c8 * 8] = s;
        }
        __syncthreads();
        // out GEMM: 2 row-tiles x 3 col-groups; wave wv takes tasks wv, wv+4
        for (int tk = wv; tk < 6; tk += 4) {
            int rt = tk / 3, cg = tk % 3;
            int ocol = cg * 16 + ln;
            bool okc = ocol < NCLASS;
            half8 bw0, bw1;
            #pragma unroll
            for (int j = 0; j < 8; ++j) {
                bw0[j] = okc ? (_Float16)Wz[(lg * 8 + j) * NCLASS + ocol] : (_Float16)0.f;
                bw1[j] = okc ? (_Float16)Wz[(32 + lg * 8 + j) * NCLASS + ocol] : (_Float16)0.f;
            }
            float bbz = okc ? bz[ocol] : 0.f;
            floatx4 ac = {0.f, 0.f, 0.f, 0.f};
            half8 a0 = *(const half8*)&z[rt * 16 + ln][lg * 8];
            ac = __builtin_amdgcn_mfma_f32_16x16x32_f16(a0, bw0, ac, 0, 0, 0);
            a0 = *(const half8*)&z[rt * 16 + ln][32 + lg * 8];
            ac = __builtin_amdgcn_mfma_f32_16x16x32_f16(a0, bw1, ac, 0, 0, 0);
            #pragma unroll
            for (int r = 0; r < 4; ++r)
                oout[rt * 16 + lg * 4 + r][cg * 16 + ln] = fmaxf(ac[r] + bbz, 0.f);
        }
        __syncthreads();
        for (int i = t; i < 32 * NCLASS; i += 256) {
            int row = i / NCLASS, ocol = i % NCLASS;
            int onode = nb + row;
            if (onode < N)
                outp[(size_t)onode * NCLASS + ocol] = oout[row][ocol];
        }
    }
}

extern "C" void kernel_launch(void* const* d_in, const int* in_sizes, int n_in,
                              void* d_out, int out_size, void* d_ws, size_t ws_size,
                              hipStream_t stream) {
    const float* x  = (const float*)d_in[0];
    const int*   ei = (const int*)d_in[1];
    const float* Wx = (const float*)d_in[2];
    const float* bx = (const float*)d_in[3];
    const float* W1 = (const float*)d_in[4];
    const float* b1 = (const float*)d_in[5];
    const float* W2 = (const float*)d_in[6];
    const float* b2 = (const float*)d_in[7];
    const float* W3 = (const float*)d_in[8];
    const float* b3 = (const float*)d_in[9];
    const float* Wz = (const float*)d_in[10];
    const float* bz = (const float*)d_in[11];
    float* out = (float*)d_out;

    int N = in_sizes[0] / NFEAT;
    int E = in_sizes[1] / 2;
    const int* src = ei;
    const int* dst = ei + E;
    int nbuckets = (N + 511) >> 9;   // 196 for N=100000

    size_t nh = (size_t)N * HID;
    size_t Npad = ((size_t)N + 7) / 8 * 8;
    // 4B-unit layout: bcur | dinv | pk | H0 | L1 | L2 | L3 | bwords | csr | Wt16 | normf
    int*      bcur = (int*)d_ws;
    float*    dinv = (float*)d_ws + 256;
    unsigned* pk   = (unsigned*)(dinv + Npad);
    _Float16* H0   = (_Float16*)(pk + Npad);
    _Float16* L1   = H0 + nh;
    _Float16* L2   = L1 + nh;
    _Float16* L3   = L2 + nh;
    int*      bwords = (int*)(L3 + nh);
    int*      csr  = bwords + (size_t)nbuckets * BCAP;
    _Float16* Wt16 = (_Float16*)(csr + (size_t)nbuckets * BCAP);
    float*    normf = (float*)(Wt16 + 3 * 4096);

    int nbin = (E + EPB - 1) / EPB;
    int ngemm = 512;
    hipMemsetAsync(bcur, 0, 256 * sizeof(int), stream);
    k_pre<<<nbin + 3 + ngemm, 256, 0, stream>>>(src, dst, bcur, bwords, nbuckets, E, nbin,
                                                W1, W2, W3, Wt16, x, Wx, bx, H0, N, ngemm);
    k_csr<<<nbuckets, 256, 0, stream>>>(bcur, bwords, csr, pk, dinv, N);

    int layer_blocks = (N + 31) / 32;
    k_layer<1,0><<<layer_blocks, 256, 0, stream>>>(H0, csr, pk, dinv, Wt16,        b1, normf, L1, N,
                                                   nullptr, nullptr, nullptr, nullptr, nullptr);
    k_layer<0,0><<<layer_blocks, 256, 0, stream>>>(L1, csr, pk, dinv, Wt16 + 4096, b2, normf, L2, N,
                                                   nullptr, nullptr, nullptr, nullptr, nullptr);
    k_layer<0,1><<<layer_blocks, 256, 0, stream>>>(L2, csr, pk, dinv, Wt16 + 8192, b3, normf, L3, N,
                                                   L1, L2, Wz, bz, out);
}

// Round 9
// 308.758 us; speedup vs baseline: 1.1467x; 1.0439x over previous
//
#include <hip/hip_runtime.h>

#define NFEAT 256
#define HID 64
#define NCLASS 40
#define EPB 4096        // edges per binning block
#define BCAP 8192       // per-bucket capacity (words / csr entries)

typedef _Float16 half8 __attribute__((ext_vector_type(8)));
typedef float floatx4 __attribute__((ext_vector_type(4)));

struct BinSM {
    int lcnt[256], loff[256], lcur[256], gbase[256], sc[256];
    int sdst[EPB];
    int words[EPB];
};

// ---------- fused preprocessing: edge binning + W1..3 fp16^T convert + h0 GEMM ----------
// blocks [0, nbin): bin edges into 512-node buckets
// blocks [nbin, nbin+3): convert W_l to fp16 transposed
// blocks [nbin+3, nbin+3+ngemm): h0 = relu(x @ Wx + bx) via MFMA
__global__ __launch_bounds__(256) void k_pre(const int* __restrict__ src, const int* __restrict__ dst,
                                             int* __restrict__ bcur, int* __restrict__ bwords,
                                             int nbuckets, int E, int nbin,
                                             const float* __restrict__ W1, const float* __restrict__ W2,
                                             const float* __restrict__ W3, _Float16* __restrict__ Wt16,
                                             const float* __restrict__ x, const float* __restrict__ Wx,
                                             const float* __restrict__ bx, _Float16* __restrict__ h0,
                                             int N, int ngemm) {
    __shared__ __align__(16) char smraw[sizeof(BinSM)];   // 37.9 KB, overlaid views
    int t = threadIdx.x;
    int bid = blockIdx.x;

    if (bid >= nbin && bid < nbin + 3) {
        // W conversion: wt[col*64 + k] = (fp16) W[k*64 + col]
        int l = bid - nbin;
        const float* Ws = (l == 0) ? W1 : (l == 1) ? W2 : W3;
        _Float16* wt = Wt16 + l * 4096;
        for (int i = t; i < 4096; i += 256) {
            int col = i >> 6, k = i & 63;
            wt[i] = (_Float16)Ws[k * HID + col];
        }
        return;
    }

    if (bid >= nbin + 3) {
        // ---- h0 GEMM part ----
        _Float16 (*Wt)[264] = (_Float16 (*)[264])smraw;   // 64 x 264 fp16 = 33.8 KB
        {
            int c = t & 63, k0 = (t >> 6) * 64;
            for (int k = k0; k < k0 + 64; ++k)
                Wt[c][k] = (_Float16)Wx[k * HID + c];
        }
        __syncthreads();
        int lane = t & 63, wv = t >> 6;
        int lg = lane >> 4, ln = lane & 15;
        int gb = bid - nbin - 3;
        int wid = gb * 4 + wv;
        int nw = ngemm * 4;
        float bb[4];
        #pragma unroll
        for (int g = 0; g < 4; ++g) bb[g] = bx[g * 16 + ln];
        int ntiles = N >> 4;
        for (int tile = wid; tile < ntiles; tile += nw) {
            int row0 = tile << 4;
            const float* xr = x + (size_t)(row0 + ln) * NFEAT + lg * 8;
            float4 av[16];
            #pragma unroll
            for (int ks = 0; ks < 8; ++ks) {
                av[2 * ks]     = *(const float4*)(xr + ks * 32);
                av[2 * ks + 1] = *(const float4*)(xr + ks * 32 + 4);
            }
            floatx4 acc[4] = {{0.f,0.f,0.f,0.f},{0.f,0.f,0.f,0.f},{0.f,0.f,0.f,0.f},{0.f,0.f,0.f,0.f}};
            #pragma unroll
            for (int ks = 0; ks < 8; ++ks) {
                float4 a0 = av[2 * ks], a1 = av[2 * ks + 1];
                half8 a;
                a[0]=(_Float16)a0.x; a[1]=(_Float16)a0.y; a[2]=(_Float16)a0.z; a[3]=(_Float16)a0.w;
                a[4]=(_Float16)a1.x; a[5]=(_Float16)a1.y; a[6]=(_Float16)a1.z; a[7]=(_Float16)a1.w;
                #pragma unroll
                for (int g = 0; g < 4; ++g) {
                    half8 b = *(const half8*)&Wt[g * 16 + ln][ks * 32 + lg * 8];
                    acc[g] = __builtin_amdgcn_mfma_f32_16x16x32_f16(a, b, acc[g], 0, 0, 0);
                }
            }
            #pragma unroll
            for (int g = 0; g < 4; ++g) {
                #pragma unroll
                for (int r = 0; r < 4; ++r) {
                    int row = row0 + lg * 4 + r;
                    h0[(size_t)row * HID + g * 16 + ln] = (_Float16)fmaxf(acc[g][r] + bb[g], 0.f);
                }
            }
        }
        return;
    }

    // ---- binning part ----
    BinSM* sm = (BinSM*)smraw;
    int base = bid * EPB;
    int n = E - base; if (n > EPB) n = EPB;
    sm->lcnt[t] = 0;
    __syncthreads();
    for (int i = t; i < n; i += 256) {
        int d = dst[base + i];
        sm->sdst[i] = d;
        atomicAdd(&sm->lcnt[d >> 9], 1);
    }
    __syncthreads();
    int v = sm->lcnt[t];
    sm->sc[t] = v; __syncthreads();
    for (int o = 1; o < 256; o <<= 1) {
        int add = (t >= o) ? sm->sc[t - o] : 0;
        __syncthreads();
        sm->sc[t] += add;
        __syncthreads();
    }
    int excl = sm->sc[t] - v;
    sm->loff[t] = excl; sm->lcur[t] = excl;
    __syncthreads();
    for (int i = t; i < n; i += 256) {
        int d = sm->sdst[i], s = src[base + i];
        int b = d >> 9;
        int p = atomicAdd(&sm->lcur[b], 1);
        sm->words[p] = s | ((d & 511) << 17);     // s < 2^17
    }
    __syncthreads();
    if (t < nbuckets) {
        int c = sm->lcnt[t];
        sm->gbase[t] = c > 0 ? atomicAdd(&bcur[t], c) : 0;
    }
    __syncthreads();
    int lane = t & 63, wv = t >> 6;
    for (int b = wv; b < nbuckets; b += 4) {
        int o = sm->loff[b], c = sm->lcnt[b], gb = sm->gbase[b];
        int* dstp = bwords + (size_t)b * BCAP;
        for (int i = lane; i < c; i += 64) {
            int gp = gb + i;
            if (gp < BCAP) dstp[gp] = sm->words[o + i];
        }
    }
}

// ---------- phase 2: per-bucket CSR build + pk/dinv ----------
__global__ __launch_bounds__(256) void k_csr(const int* __restrict__ bcur, const int* __restrict__ bwords,
                                             int* __restrict__ csr, unsigned* __restrict__ pk,
                                             float* __restrict__ dinv, int N) {
    __shared__ int cnt[512], cur[512], sc[256];
    __shared__ int lcsr[BCAP];     // 32 KB
    int t = threadIdx.x;
    int b = blockIdx.x;
    int nodebase = b << 9;
    int nb = bcur[b]; if (nb > BCAP) nb = BCAP;
    cnt[t] = 0; cnt[t + 256] = 0;
    __syncthreads();
    const int* wp = bwords + (size_t)b * BCAP;
    for (int i = t; i < nb; i += 256)
        atomicAdd(&cnt[wp[i] >> 17], 1);
    __syncthreads();
    int v0 = cnt[2 * t], v1 = cnt[2 * t + 1];
    int p = v0 + v1;
    sc[t] = p; __syncthreads();
    for (int o = 1; o < 256; o <<= 1) {
        int add = (t >= o) ? sc[t - o] : 0;
        __syncthreads();
        sc[t] += add;
        __syncthreads();
    }
    int e = sc[t] - p;
    cur[2 * t] = e; cur[2 * t + 1] = e + v0;
    #pragma unroll
    for (int j = 0; j < 2; ++j) {
        int node = nodebase + 2 * t + j;
        if (node < N) {
            int c = cnt[2 * t + j]; if (c > 2047) c = 2047;
            pk[node] = (unsigned)(b * BCAP + cur[2 * t + j]) | ((unsigned)c << 21);
            dinv[node] = rsqrtf((float)c + 1.0f);
        }
    }
    __syncthreads();
    for (int i = t; i < nb; i += 256) {
        int w = wp[i];
        int pos = atomicAdd(&cur[w >> 17], 1);
        lcsr[pos] = w & 0x1FFFF;
    }
    __syncthreads();
    int* cp = csr + (size_t)b * BCAP;
    for (int i = t; i < nb; i += 256) cp[i] = lcsr[i];
}

// ---------- fused GCN layer: dual-stream gather (2 independent nodes per subgroup) ----------
// block = 256 thr = 4 waves = 64 nodes; wave = 8 subgroups x 8 lanes; subgroup sg owns nodes
// (wv*16+sg) and (wv*16+8+sg). The two nodes' chunk chains are independent -> 16 row-loads
// in flight per lane-iteration instead of 8, hiding L2/L3 gather latency (MLP doubling).
// csr/norm for chunk k+1 prefetched during chunk k's consume (as in R4).
template<int WRN>
__global__ __launch_bounds__(256) void k_layer(const _Float16* __restrict__ Ph, const int* __restrict__ csr,
                                               const unsigned* __restrict__ pk, const float* __restrict__ dinv,
                                               const _Float16* __restrict__ Wt, const float* __restrict__ b,
                                               float* __restrict__ normf,
                                               _Float16* __restrict__ Lout, int N) {
    __shared__ _Float16 z[64][72];     // aggregated features (9.2 KB)
    __shared__ _Float16 ot[64][72];    // output tile (9.2 KB)
    int t = threadIdx.x;
    int lane = t & 63, wv = t >> 6;
    int sg = lane >> 3, f8 = lane & 7;
    int lg = lane >> 4, ln = lane & 15;
    int nb = blockIdx.x << 6;
    int node0 = nb + wv * 16 + sg;
    int node1 = node0 + 8;
    bool va0 = node0 < N, va1 = node1 < N;
    int nc0 = va0 ? node0 : (N - 1);
    int nc1 = va1 ? node1 : (N - 1);
    // B fragment from pre-converted fp16 W^T: 2 x half8 loads
    int col = wv * 16 + ln;
    half8 bf0 = *(const half8*)(Wt + col * 64 + lg * 8);
    half8 bf1 = *(const half8*)(Wt + col * 64 + 32 + lg * 8);
    float bb = b[col];

    unsigned pv0 = va0 ? pk[node0] : 0u;
    unsigned pv1 = va1 ? pk[node1] : 0u;
    int off0 = (int)(pv0 & 0x1FFFFFu), c0 = va0 ? (int)(pv0 >> 21) : 0;
    int off1 = (int)(pv1 & 0x1FFFFFu), c1 = va1 ? (int)(pv1 >> 21) : 0;
    float dd0 = va0 ? dinv[node0] : 0.f;
    float dd1 = va1 ? dinv[node1] : 0.f;
    const _Float16* pb = Ph + f8 * 8;
    float a0[8], a1[8];
    {
        half8 s0 = *(const half8*)(pb + (size_t)nc0 * HID);
        half8 s1 = *(const half8*)(pb + (size_t)nc1 * HID);
        float d20 = dd0 * dd0, d21 = dd1 * dd1;
        #pragma unroll
        for (int j = 0; j < 8; ++j) { a0[j] = (float)s0[j] * d20; a1[j] = (float)s1[j] * d21; }
    }
    // prologue: chunk 0's edge data for both streams
    int e0 = f8;
    bool ok0 = e0 < c0, ok1 = e0 < c1;
    int s0 = ok0 ? csr[off0 + e0] : nc0;
    int s1 = ok1 ? csr[off1 + e0] : nc1;
    float nm0, nm1;
    if (WRN) {
        nm0 = ok0 ? dinv[s0] * dd0 : 0.f; if (ok0) normf[off0 + e0] = nm0;
        nm1 = ok1 ? dinv[s1] * dd1 : 0.f; if (ok1) normf[off1 + e0] = nm1;
    } else {
        nm0 = ok0 ? normf[off0 + e0] : 0.f;
        nm1 = ok1 ? normf[off1 + e0] : 0.f;
    }
    int cmax = c0 > c1 ? c0 : c1;
    for (int jj = 0; jj < cmax; jj += 8) {
        // prefetch next chunk's csr/norm for both streams (hidden under consume)
        int en = jj + 8 + f8;
        bool okn0 = en < c0, okn1 = en < c1;
        int t0 = okn0 ? csr[off0 + en] : nc0;
        int t1 = okn1 ? csr[off1 + en] : nc1;
        float tn0, tn1;
        if (WRN) {
            tn0 = okn0 ? dinv[t0] * dd0 : 0.f; if (okn0) normf[off0 + en] = tn0;
            tn1 = okn1 ? dinv[t1] * dd1 : 0.f; if (okn1) normf[off1 + en] = tn1;
        } else {
            tn0 = okn0 ? normf[off0 + en] : 0.f;
            tn1 = okn1 ? normf[off1 + en] : 0.f;
        }
        // consume current chunk: 8+8 interleaved independent row loads
        #pragma unroll
        for (int j = 0; j < 8; ++j) {
            int ss0 = __shfl(s0, j, 8);
            int ss1 = __shfl(s1, j, 8);
            half8 v0 = *(const half8*)(pb + (size_t)ss0 * HID);
            half8 v1 = *(const half8*)(pb + (size_t)ss1 * HID);
            float n0 = __shfl(nm0, j, 8);
            float n1 = __shfl(nm1, j, 8);
            #pragma unroll
            for (int q = 0; q < 8; ++q) a0[q] = fmaf((float)v0[q], n0, a0[q]);
            #pragma unroll
            for (int q = 0; q < 8; ++q) a1[q] = fmaf((float)v1[q], n1, a1[q]);
        }
        s0 = t0; nm0 = tn0; s1 = t1; nm1 = tn1;
    }
    {
        half8 zv0, zv1;
        #pragma unroll
        for (int j = 0; j < 8; ++j) { zv0[j] = (_Float16)a0[j]; zv1[j] = (_Float16)a1[j]; }
        *(half8*)&z[wv * 16 + sg][f8 * 8] = zv0;
        *(half8*)&z[wv * 16 + 8 + sg][f8 * 8] = zv1;
    }
    __syncthreads();
    // MFMA: four 16-row tiles; ot[rows][wv*16 .. +15] = z @ W + b
    #pragma unroll
    for (int rt = 0; rt < 4; ++rt) {
        floatx4 ac = {0.f, 0.f, 0.f, 0.f};
        half8 av = *(const half8*)&z[rt * 16 + ln][lg * 8];
        ac = __builtin_amdgcn_mfma_f32_16x16x32_f16(av, bf0, ac, 0, 0, 0);
        av = *(const half8*)&z[rt * 16 + ln][32 + lg * 8];
        ac = __builtin_amdgcn_mfma_f32_16x16x32_f16(av, bf1, ac, 0, 0, 0);
        #pragma unroll
        for (int r = 0; r < 4; ++r)
            ot[rt * 16 + lg * 4 + r][wv * 16 + ln] = (_Float16)(ac[r] + bb);
    }
    __syncthreads();
    // coalesced store of the 64x64 fp16 tile: 512 half8 tasks, 2 per thread
    #pragma unroll
    for (int i = t; i < 512; i += 256) {
        int row = i >> 3, c8 = i & 7;
        int onode = nb + row;
        if (onode < N)
            *(half8*)(Lout + (size_t)onode * HID + c8 * 8) = *(const half8*)&ot[row][c8 * 8];
    }
}

// ---------- out = relu(((L1+L2+L3)/3) @ Wz + bz) ----------
__global__ __launch_bounds__(256) void k_gemm_out(const _Float16* __restrict__ L1, const _Float16* __restrict__ L2,
                                                  const _Float16* __restrict__ L3, const float* __restrict__ Wz,
                                                  const float* __restrict__ bz, float* __restrict__ outp, int N) {
    int t = threadIdx.x;
    int lane = t & 63, lg = lane >> 4, ln = lane & 15;
    int wid = (blockIdx.x * 256 + t) >> 6;
    int nw = (gridDim.x * 256) >> 6;
    half8 b[2][3];
    float bb[3];
    #pragma unroll
    for (int g = 0; g < 3; ++g) {
        int col = g * 16 + ln;
        bb[g] = (col < NCLASS) ? bz[col] : 0.f;
        #pragma unroll
        for (int ks = 0; ks < 2; ++ks)
            #pragma unroll
            for (int j = 0; j < 8; ++j)
                b[ks][g][j] = (col < NCLASS) ? (_Float16)(Wz[(ks * 32 + lg * 8 + j) * NCLASS + col] * (1.f / 3.f)) : (_Float16)0.f;
    }
    int ntiles = N >> 4;
    for (int tile = wid; tile < ntiles; tile += nw) {
        int row0 = tile << 4;
        size_t rb = (size_t)(row0 + ln) * HID + lg * 8;
        floatx4 acc[3] = {{0.f,0.f,0.f,0.f},{0.f,0.f,0.f,0.f},{0.f,0.f,0.f,0.f}};
        #pragma unroll
        for (int ks = 0; ks < 2; ++ks) {
            half8 a1 = *(const half8*)(L1 + rb + ks * 32);
            half8 a2 = *(const half8*)(L2 + rb + ks * 32);
            half8 a3 = *(const half8*)(L3 + rb + ks * 32);
            half8 a;
            #pragma unroll
            for (int j = 0; j < 8; ++j)
                a[j] = (_Float16)((float)a1[j] + (float)a2[j] + (float)a3[j]);
            #pragma unroll
            for (int g = 0; g < 3; ++g)
                acc[g] = __builtin_amdgcn_mfma_f32_16x16x32_f16(a, b[ks][g], acc[g], 0, 0, 0);
        }
        #pragma unroll
        for (int g = 0; g < 3; ++g) {
            int col = g * 16 + ln;
            if (col < NCLASS) {
                #pragma unroll
                for (int r = 0; r < 4; ++r)
                    outp[(size_t)(row0 + lg * 4 + r) * NCLASS + col] = fmaxf(acc[g][r] + bb[g], 0.f);
            }
        }
    }
}

extern "C" void kernel_launch(void* const* d_in, const int* in_sizes, int n_in,
                              void* d_out, int out_size, void* d_ws, size_t ws_size,
                              hipStream_t stream) {
    const float* x  = (const float*)d_in[0];
    const int*   ei = (const int*)d_in[1];
    const float* Wx = (const float*)d_in[2];
    const float* bx = (const float*)d_in[3];
    const float* W1 = (const float*)d_in[4];
    const float* b1 = (const float*)d_in[5];
    const float* W2 = (const float*)d_in[6];
    const float* b2 = (const float*)d_in[7];
    const float* W3 = (const float*)d_in[8];
    const float* b3 = (const float*)d_in[9];
    const float* Wz = (const float*)d_in[10];
    const float* bz = (const float*)d_in[11];
    float* out = (float*)d_out;

    int N = in_sizes[0] / NFEAT;
    int E = in_sizes[1] / 2;
    const int* src = ei;
    const int* dst = ei + E;
    int nbuckets = (N + 511) >> 9;   // 196 for N=100000 (<=256)

    size_t nh = (size_t)N * HID;
    size_t Npad = ((size_t)N + 7) / 8 * 8;
    // 4B-unit layout: bcur[256] | dinv | pk | H0 | L1 | L2 | L3 | bwords | csr | Wt16 | normf
    int*      bcur = (int*)d_ws;
    float*    dinv = (float*)d_ws + 256;
    unsigned* pk   = (unsigned*)(dinv + Npad);
    _Float16* H0   = (_Float16*)(pk + Npad);
    _Float16* L1   = H0 + nh;
    _Float16* L2   = L1 + nh;
    _Float16* L3   = L2 + nh;
    int*      bwords = (int*)(L3 + nh);
    int*      csr  = bwords + (size_t)nbuckets * BCAP;
    _Float16* Wt16 = (_Float16*)(csr + (size_t)nbuckets * BCAP);
    float*    normf = (float*)(Wt16 + 3 * 4096);

    int nbin = (E + EPB - 1) / EPB;
    int ngemm = 512;
    hipMemsetAsync(bcur, 0, 256 * sizeof(int), stream);
    k_pre<<<nbin + 3 + ngemm, 256, 0, stream>>>(src, dst, bcur, bwords, nbuckets, E, nbin,
                                                W1, W2, W3, Wt16, x, Wx, bx, H0, N, ngemm);
    k_csr<<<nbuckets, 256, 0, stream>>>(bcur, bwords, csr, pk, dinv, N);

    int layer_blocks = (N + 63) / 64;
    k_layer<1><<<layer_blocks, 256, 0, stream>>>(H0, csr, pk, dinv, Wt16,          b1, normf, L1, N);
    k_layer<0><<<layer_blocks, 256, 0, stream>>>(L1, csr, pk, dinv, Wt16 + 4096,   b2, normf, L2, N);
    k_layer<0><<<layer_blocks, 256, 0, stream>>>(L2, csr, pk, dinv, Wt16 + 8192,   b3, normf, L3, N);

    k_gemm_out<<<512, 256, 0, stream>>>(L1, L2, L3, Wz, bz, out, N);
}

// Round 10
// 302.186 us; speedup vs baseline: 1.1716x; 1.0217x over previous
//
#include <hip/hip_runtime.h>

#define NFEAT 256
#define HID 64
#define NCLASS 40
#define EPB 4096        // edges per binning block
#define BCAP 8192       // per-bucket capacity (words / csr entries)

typedef _Float16 half8 __attribute__((ext_vector_type(8)));
typedef float floatx4 __attribute__((ext_vector_type(4)));

struct BinSM {
    int lcnt[256], loff[256], lcur[256], gbase[256], sc[256];
    int sdst[EPB];
    int words[EPB];
};

// ---------- fused preprocessing: edge binning + W1..3 fp16^T convert + h0 GEMM ----------
// blocks [0, nbin): bin edges into 512-node buckets
// blocks [nbin, nbin+3): convert W_l to fp16 transposed
// blocks [nbin+3, nbin+3+ngemm): h0 = relu(x @ Wx + bx) via MFMA
__global__ __launch_bounds__(256) void k_pre(const int* __restrict__ src, const int* __restrict__ dst,
                                             int* __restrict__ bcur, int* __restrict__ bwords,
                                             int nbuckets, int E, int nbin,
                                             const float* __restrict__ W1, const float* __restrict__ W2,
                                             const float* __restrict__ W3, _Float16* __restrict__ Wt16,
                                             const float* __restrict__ x, const float* __restrict__ Wx,
                                             const float* __restrict__ bx, _Float16* __restrict__ h0,
                                             int N, int ngemm) {
    __shared__ __align__(16) char smraw[sizeof(BinSM)];   // 37.9 KB, overlaid views
    int t = threadIdx.x;
    int bid = blockIdx.x;

    if (bid >= nbin && bid < nbin + 3) {
        // W conversion: wt[col*64 + k] = (fp16) W[k*64 + col]
        int l = bid - nbin;
        const float* Ws = (l == 0) ? W1 : (l == 1) ? W2 : W3;
        _Float16* wt = Wt16 + l * 4096;
        for (int i = t; i < 4096; i += 256) {
            int col = i >> 6, k = i & 63;
            wt[i] = (_Float16)Ws[k * HID + col];
        }
        return;
    }

    if (bid >= nbin + 3) {
        // ---- h0 GEMM part ----
        _Float16 (*Wt)[264] = (_Float16 (*)[264])smraw;   // 64 x 264 fp16 = 33.8 KB
        // coalesced float4 staging: 16 vector loads/thread instead of 64 scalar strided
        for (int i = t; i < 4096; i += 256) {
            int k = i >> 4, c4 = (i & 15) << 2;
            float4 w = *(const float4*)(Wx + k * HID + c4);
            Wt[c4][k]     = (_Float16)w.x;
            Wt[c4 + 1][k] = (_Float16)w.y;
            Wt[c4 + 2][k] = (_Float16)w.z;
            Wt[c4 + 3][k] = (_Float16)w.w;
        }
        __syncthreads();
        int lane = t & 63, wv = t >> 6;
        int lg = lane >> 4, ln = lane & 15;
        int gb = bid - nbin - 3;
        int wid = gb * 4 + wv;
        int nw = ngemm * 4;
        float bb[4];
        #pragma unroll
        for (int g = 0; g < 4; ++g) bb[g] = bx[g * 16 + ln];
        int ntiles = N >> 4;
        for (int tile = wid; tile < ntiles; tile += nw) {
            int row0 = tile << 4;
            const float* xr = x + (size_t)(row0 + ln) * NFEAT + lg * 8;
            float4 av[16];
            #pragma unroll
            for (int ks = 0; ks < 8; ++ks) {
                av[2 * ks]     = *(const float4*)(xr + ks * 32);
                av[2 * ks + 1] = *(const float4*)(xr + ks * 32 + 4);
            }
            floatx4 acc[4] = {{0.f,0.f,0.f,0.f},{0.f,0.f,0.f,0.f},{0.f,0.f,0.f,0.f},{0.f,0.f,0.f,0.f}};
            #pragma unroll
            for (int ks = 0; ks < 8; ++ks) {
                float4 a0 = av[2 * ks], a1 = av[2 * ks + 1];
                half8 a;
                a[0]=(_Float16)a0.x; a[1]=(_Float16)a0.y; a[2]=(_Float16)a0.z; a[3]=(_Float16)a0.w;
                a[4]=(_Float16)a1.x; a[5]=(_Float16)a1.y; a[6]=(_Float16)a1.z; a[7]=(_Float16)a1.w;
                #pragma unroll
                for (int g = 0; g < 4; ++g) {
                    half8 b = *(const half8*)&Wt[g * 16 + ln][ks * 32 + lg * 8];
                    acc[g] = __builtin_amdgcn_mfma_f32_16x16x32_f16(a, b, acc[g], 0, 0, 0);
                }
            }
            #pragma unroll
            for (int g = 0; g < 4; ++g) {
                #pragma unroll
                for (int r = 0; r < 4; ++r) {
                    int row = row0 + lg * 4 + r;
                    h0[(size_t)row * HID + g * 16 + ln] = (_Float16)fmaxf(acc[g][r] + bb[g], 0.f);
                }
            }
        }
        return;
    }

    // ---- binning part ----
    BinSM* sm = (BinSM*)smraw;
    int base = bid * EPB;
    int n = E - base; if (n > EPB) n = EPB;
    sm->lcnt[t] = 0;
    __syncthreads();
    for (int i = t; i < n; i += 256) {
        int d = dst[base + i];
        sm->sdst[i] = d;
        atomicAdd(&sm->lcnt[d >> 9], 1);
    }
    __syncthreads();
    int v = sm->lcnt[t];
    sm->sc[t] = v; __syncthreads();
    for (int o = 1; o < 256; o <<= 1) {
        int add = (t >= o) ? sm->sc[t - o] : 0;
        __syncthreads();
        sm->sc[t] += add;
        __syncthreads();
    }
    int excl = sm->sc[t] - v;
    sm->loff[t] = excl; sm->lcur[t] = excl;
    __syncthreads();
    for (int i = t; i < n; i += 256) {
        int d = sm->sdst[i], s = src[base + i];
        int b = d >> 9;
        int p = atomicAdd(&sm->lcur[b], 1);
        sm->words[p] = s | ((d & 511) << 17);     // s < 2^17
    }
    __syncthreads();
    if (t < nbuckets) {
        int c = sm->lcnt[t];
        sm->gbase[t] = c > 0 ? atomicAdd(&bcur[t], c) : 0;
    }
    __syncthreads();
    int lane = t & 63, wv = t >> 6;
    for (int b = wv; b < nbuckets; b += 4) {
        int o = sm->loff[b], c = sm->lcnt[b], gb = sm->gbase[b];
        int* dstp = bwords + (size_t)b * BCAP;
        for (int i = lane; i < c; i += 64) {
            int gp = gb + i;
            if (gp < BCAP) dstp[gp] = sm->words[o + i];
        }
    }
}

// ---------- phase 2: per-bucket CSR build + pk/dinv ----------
__global__ __launch_bounds__(256) void k_csr(const int* __restrict__ bcur, const int* __restrict__ bwords,
                                             int* __restrict__ csr, unsigned* __restrict__ pk,
                                             float* __restrict__ dinv, int N) {
    __shared__ int cnt[512], cur[512], sc[256];
    __shared__ int lcsr[BCAP];     // 32 KB
    int t = threadIdx.x;
    int b = blockIdx.x;
    int nodebase = b << 9;
    int nb = bcur[b]; if (nb > BCAP) nb = BCAP;
    cnt[t] = 0; cnt[t + 256] = 0;
    __syncthreads();
    const int* wp = bwords + (size_t)b * BCAP;
    for (int i = t; i < nb; i += 256)
        atomicAdd(&cnt[wp[i] >> 17], 1);
    __syncthreads();
    int v0 = cnt[2 * t], v1 = cnt[2 * t + 1];
    int p = v0 + v1;
    sc[t] = p; __syncthreads();
    for (int o = 1; o < 256; o <<= 1) {
        int add = (t >= o) ? sc[t - o] : 0;
        __syncthreads();
        sc[t] += add;
        __syncthreads();
    }
    int e = sc[t] - p;
    cur[2 * t] = e; cur[2 * t + 1] = e + v0;
    #pragma unroll
    for (int j = 0; j < 2; ++j) {
        int node = nodebase + 2 * t + j;
        if (node < N) {
            int c = cnt[2 * t + j]; if (c > 2047) c = 2047;
            pk[node] = (unsigned)(b * BCAP + cur[2 * t + j]) | ((unsigned)c << 21);
            dinv[node] = rsqrtf((float)c + 1.0f);
        }
    }
    __syncthreads();
    for (int i = t; i < nb; i += 256) {
        int w = wp[i];
        int pos = atomicAdd(&cur[w >> 17], 1);
        lcsr[pos] = w & 0x1FFFF;
    }
    __syncthreads();
    int* cp = csr + (size_t)b * BCAP;
    for (int i = t; i < nb; i += 256) cp[i] = lcsr[i];
}

// ---------- fused GCN layer: z = A·h (gather+self), then out = z@W + b via MFMA ----------
// block = 256 thr = 4 waves = 32 nodes; wave = 8 subgroups x 8 lanes (sg owns node, f8 owns
// 16B feature seg). VGPR gathers (8 rows/chunk in flight); next chunk's csr/norm prefetched
// during consume to hide the serial csr->norm chain. WRN=1: compute+cache norm; WRN=0: load it.
template<int WRN>
__global__ __launch_bounds__(256) void k_layer(const _Float16* __restrict__ Ph, const int* __restrict__ csr,
                                               const unsigned* __restrict__ pk, const float* __restrict__ dinv,
                                               const _Float16* __restrict__ Wt, const float* __restrict__ b,
                                               float* __restrict__ normf,
                                               _Float16* __restrict__ Lout, int N) {
    __shared__ _Float16 z[32][72];     // aggregated features
    __shared__ _Float16 ot[32][72];    // output tile
    int t = threadIdx.x;
    int lane = t & 63, wv = t >> 6;
    int sg = lane >> 3, f8 = lane & 7;
    int lg = lane >> 4, ln = lane & 15;
    int nb = blockIdx.x << 5;
    int node = nb + wv * 8 + sg;
    bool valid = node < N;
    int nodec = valid ? node : (N - 1);
    // B fragment from pre-converted fp16 W^T: 2 x half8 loads
    int col = wv * 16 + ln;
    half8 bf0 = *(const half8*)(Wt + col * 64 + lg * 8);
    half8 bf1 = *(const half8*)(Wt + col * 64 + 32 + lg * 8);
    float bb = b[col];

    unsigned pkv = valid ? pk[node] : 0u;
    int off = (int)(pkv & 0x1FFFFFu);
    int c = valid ? (int)(pkv >> 21) : 0;
    float dd = valid ? dinv[node] : 0.f;
    const _Float16* pb = Ph + f8 * 8;
    float acc[8];
    {
        half8 self = *(const half8*)(pb + (size_t)nodec * HID);
        float dd2 = dd * dd;
        #pragma unroll
        for (int j = 0; j < 8; ++j) acc[j] = (float)self[j] * dd2;
    }
    // prologue: chunk 0's edge data
    int ecur = f8;
    bool ok = ecur < c;
    int s_cur = ok ? csr[off + ecur] : nodec;
    float nm_cur;
    if (WRN) {
        nm_cur = ok ? dinv[s_cur] * dd : 0.f;
        if (ok) normf[off + ecur] = nm_cur;
    } else {
        nm_cur = ok ? normf[off + ecur] : 0.f;
    }
    for (int jj = 0; jj < c; jj += 8) {
        // prefetch next chunk's csr/norm (latency hidden under consume below)
        int en = jj + 8 + f8;
        bool okn = en < c;
        int s_nxt = okn ? csr[off + en] : nodec;
        float nm_nxt;
        if (WRN) {
            nm_nxt = okn ? dinv[s_nxt] * dd : 0.f;
            if (okn) normf[off + en] = nm_nxt;
        } else {
            nm_nxt = okn ? normf[off + en] : 0.f;
        }
        // consume current chunk: 8 broadcast rows
        #pragma unroll
        for (int j = 0; j < 8; ++j) {
            int ss = __shfl(s_cur, j, 8);
            float nn = __shfl(nm_cur, j, 8);
            half8 v = *(const half8*)(pb + (size_t)ss * HID);
            #pragma unroll
            for (int q = 0; q < 8; ++q) acc[q] = fmaf((float)v[q], nn, acc[q]);
        }
        s_cur = s_nxt; nm_cur = nm_nxt;
    }
    {
        half8 zv;
        #pragma unroll
        for (int j = 0; j < 8; ++j) zv[j] = (_Float16)acc[j];
        *(half8*)&z[wv * 8 + sg][f8 * 8] = zv;
    }
    __syncthreads();
    // MFMA: two 16-row tiles; out[rows][wv*16 .. wv*16+15] = z @ W
    floatx4 acc0 = {0.f, 0.f, 0.f, 0.f}, acc1 = {0.f, 0.f, 0.f, 0.f};
    {
        half8 a0 = *(const half8*)&z[ln][lg * 8];
        half8 a1 = *(const half8*)&z[16 + ln][lg * 8];
        acc0 = __builtin_amdgcn_mfma_f32_16x16x32_f16(a0, bf0, acc0, 0, 0, 0);
        acc1 = __builtin_amdgcn_mfma_f32_16x16x32_f16(a1, bf0, acc1, 0, 0, 0);
        a0 = *(const half8*)&z[ln][32 + lg * 8];
        a1 = *(const half8*)&z[16 + ln][32 + lg * 8];
        acc0 = __builtin_amdgcn_mfma_f32_16x16x32_f16(a0, bf1, acc0, 0, 0, 0);
        acc1 = __builtin_amdgcn_mfma_f32_16x16x32_f16(a1, bf1, acc1, 0, 0, 0);
    }
    #pragma unroll
    for (int r = 0; r < 4; ++r) {
        ot[lg * 4 + r][wv * 16 + ln] = (_Float16)(acc0[r] + bb);
        ot[16 + lg * 4 + r][wv * 16 + ln] = (_Float16)(acc1[r] + bb);
    }
    __syncthreads();
    // coalesced store of the 32x64 fp16 tile
    {
        int row = t >> 3, c8 = t & 7;
        int onode = nb + row;
        if (onode < N)
            *(half8*)(Lout + (size_t)onode * HID + c8 * 8) = *(const half8*)&ot[row][c8 * 8];
    }
}

// ---------- out = relu(((L1+L2+L3)/3) @ Wz + bz) ----------
__global__ __launch_bounds__(256) void k_gemm_out(const _Float16* __restrict__ L1, const _Float16* __restrict__ L2,
                                                  const _Float16* __restrict__ L3, const float* __restrict__ Wz,
                                                  const float* __restrict__ bz, float* __restrict__ outp, int N) {
    int t = threadIdx.x;
    int lane = t & 63, lg = lane >> 4, ln = lane & 15;
    int wid = (blockIdx.x * 256 + t) >> 6;
    int nw = (gridDim.x * 256) >> 6;
    half8 b[2][3];
    float bb[3];
    #pragma unroll
    for (int g = 0; g < 3; ++g) {
        int col = g * 16 + ln;
        bb[g] = (col < NCLASS) ? bz[col] : 0.f;
        #pragma unroll
        for (int ks = 0; ks < 2; ++ks)
            #pragma unroll
            for (int j = 0; j < 8; ++j)
                b[ks][g][j] = (col < NCLASS) ? (_Float16)(Wz[(ks * 32 + lg * 8 + j) * NCLASS + col] * (1.f / 3.f)) : (_Float16)0.f;
    }
    int ntiles = N >> 4;
    for (int tile = wid; tile < ntiles; tile += nw) {
        int row0 = tile << 4;
        size_t rb = (size_t)(row0 + ln) * HID + lg * 8;
        floatx4 acc[3] = {{0.f,0.f,0.f,0.f},{0.f,0.f,0.f,0.f},{0.f,0.f,0.f,0.f}};
        #pragma unroll
        for (int ks = 0; ks < 2; ++ks) {
            half8 a1 = *(const half8*)(L1 + rb + ks * 32);
            half8 a2 = *(const half8*)(L2 + rb + ks * 32);
            half8 a3 = *(const half8*)(L3 + rb + ks * 32);
            half8 a;
            #pragma unroll
            for (int j = 0; j < 8; ++j)
                a[j] = (_Float16)((float)a1[j] + (float)a2[j] + (float)a3[j]);
            #pragma unroll
            for (int g = 0; g < 3; ++g)
                acc[g] = __builtin_amdgcn_mfma_f32_16x16x32_f16(a, b[ks][g], acc[g], 0, 0, 0);
        }
        #pragma unroll
        for (int g = 0; g < 3; ++g) {
            int col = g * 16 + ln;
            if (col < NCLASS) {
                #pragma unroll
                for (int r = 0; r < 4; ++r)
                    outp[(size_t)(row0 + lg * 4 + r) * NCLASS + col] = fmaxf(acc[g][r] + bb[g], 0.f);
            }
        }
    }
}

extern "C" void kernel_launch(void* const* d_in, const int* in_sizes, int n_in,
                              void* d_out, int out_size, void* d_ws, size_t ws_size,
                              hipStream_t stream) {
    const float* x  = (const float*)d_in[0];
    const int*   ei = (const int*)d_in[1];
    const float* Wx = (const float*)d_in[2];
    const float* bx = (const float*)d_in[3];
    const float* W1 = (const float*)d_in[4];
    const float* b1 = (const float*)d_in[5];
    const float* W2 = (const float*)d_in[6];
    const float* b2 = (const float*)d_in[7];
    const float* W3 = (const float*)d_in[8];
    const float* b3 = (const float*)d_in[9];
    const float* Wz = (const float*)d_in[10];
    const float* bz = (const float*)d_in[11];
    float* out = (float*)d_out;

    int N = in_sizes[0] / NFEAT;
    int E = in_sizes[1] / 2;
    const int* src = ei;
    const int* dst = ei + E;
    int nbuckets = (N + 511) >> 9;   // 196 for N=100000 (<=256)

    size_t nh = (size_t)N * HID;
    size_t Npad = ((size_t)N + 7) / 8 * 8;
    // 4B-unit layout: bcur[256] | dinv | pk | H0 | L1 | L2 | L3 | bwords | csr | Wt16 | normf
    int*      bcur = (int*)d_ws;
    float*    dinv = (float*)d_ws + 256;
    unsigned* pk   = (unsigned*)(dinv + Npad);
    _Float16* H0   = (_Float16*)(pk + Npad);
    _Float16* L1   = H0 + nh;
    _Float16* L2   = L1 + nh;
    _Float16* L3   = L2 + nh;
    int*      bwords = (int*)(L3 + nh);
    int*      csr  = bwords + (size_t)nbuckets * BCAP;
    _Float16* Wt16 = (_Float16*)(csr + (size_t)nbuckets * BCAP);
    float*    normf = (float*)(Wt16 + 3 * 4096);

    int nbin = (E + EPB - 1) / EPB;
    int ngemm = 128;
    hipMemsetAsync(bcur, 0, 256 * sizeof(int), stream);
    k_pre<<<nbin + 3 + ngemm, 256, 0, stream>>>(src, dst, bcur, bwords, nbuckets, E, nbin,
                                                W1, W2, W3, Wt16, x, Wx, bx, H0, N, ngemm);
    k_csr<<<nbuckets, 256, 0, stream>>>(bcur, bwords, csr, pk, dinv, N);

    int layer_blocks = (N + 31) / 32;
    k_layer<1><<<layer_blocks, 256, 0, stream>>>(H0, csr, pk, dinv, Wt16,          b1, normf, L1, N);
    k_layer<0><<<layer_blocks, 256, 0, stream>>>(L1, csr, pk, dinv, Wt16 + 4096,   b2, normf, L2, N);
    k_layer<0><<<layer_blocks, 256, 0, stream>>>(L2, csr, pk, dinv, Wt16 + 8192,   b3, normf, L3, N);

    k_gemm_out<<<512, 256, 0, stream>>>(L1, L2, L3, Wz, bz, out, N);
}

// Round 11
// 292.882 us; speedup vs baseline: 1.2089x; 1.0318x over previous
//
#include <hip/hip_runtime.h>

#define NFEAT 256
#define HID 64
#define NCLASS 40
#define EPB 2048        // edges per binning block (halved: 2x parallelism, half serial passes)
#define BCAP 8192       // per-bucket capacity (words / csr entries)

typedef _Float16 half8 __attribute__((ext_vector_type(8)));
typedef float floatx4 __attribute__((ext_vector_type(4)));

// ---------- wave/block inclusive scans (2 barriers instead of 16) ----------
__device__ __forceinline__ int wave_iscan(int v, int lane) {
    #pragma unroll
    for (int o = 1; o < 64; o <<= 1) {
        int u = __shfl_up(v, o, 64);
        if (lane >= o) v += u;
    }
    return v;
}

template<int NT>
__device__ __forceinline__ int block_iscan(int v, int t, int* wsum) {
    const int NW = NT / 64;
    int lane = t & 63, wv = t >> 6;
    int s = wave_iscan(v, lane);
    if (lane == 63) wsum[wv] = s;
    __syncthreads();
    if (wv == 0) {
        int w = (lane < NW) ? wsum[lane] : 0;
        #pragma unroll
        for (int o = 1; o < NW; o <<= 1) {
            int u = __shfl_up(w, o, 64);
            if (lane >= o) w += u;
        }
        if (lane < NW) wsum[lane] = w;
    }
    __syncthreads();
    int add = (wv > 0) ? wsum[wv - 1] : 0;
    return s + add;
}

struct BinSM {
    int lcnt[256], loff[256], lcur[256], gbase[256], wsum[4];
    int sdst[EPB];
    int words[EPB];
};
// shared buffer must cover both views: BinSM (~20.6 KB) and Wt 64x264 fp16 (33.8 KB)
#define WT_BYTES (64 * 264 * 2)
#define SMSZ (sizeof(BinSM) > WT_BYTES ? sizeof(BinSM) : WT_BYTES)

// ---------- fused preprocessing: edge binning + W1..3 fp16^T convert + h0 GEMM ----------
// blocks [0, nbin): bin edges into 512-node buckets
// blocks [nbin, nbin+3): convert W_l to fp16 transposed
// blocks [nbin+3, nbin+3+ngemm): h0 = relu(x @ Wx + bx) via MFMA
__global__ __launch_bounds__(256) void k_pre(const int* __restrict__ src, const int* __restrict__ dst,
                                             int* __restrict__ bcur, int* __restrict__ bwords,
                                             int nbuckets, int E, int nbin,
                                             const float* __restrict__ W1, const float* __restrict__ W2,
                                             const float* __restrict__ W3, _Float16* __restrict__ Wt16,
                                             const float* __restrict__ x, const float* __restrict__ Wx,
                                             const float* __restrict__ bx, _Float16* __restrict__ h0,
                                             int N, int ngemm) {
    __shared__ __align__(16) char smraw[SMSZ];
    int t = threadIdx.x;
    int bid = blockIdx.x;

    if (bid >= nbin && bid < nbin + 3) {
        // W conversion: wt[col*64 + k] = (fp16) W[k*64 + col]
        int l = bid - nbin;
        const float* Ws = (l == 0) ? W1 : (l == 1) ? W2 : W3;
        _Float16* wt = Wt16 + l * 4096;
        for (int i = t; i < 4096; i += 256) {
            int col = i >> 6, k = i & 63;
            wt[i] = (_Float16)Ws[k * HID + col];
        }
        return;
    }

    if (bid >= nbin + 3) {
        // ---- h0 GEMM part (R4's scalar staging: measured 59.5 µs dispatch, no LDS-write conflicts) ----
        _Float16 (*Wt)[264] = (_Float16 (*)[264])smraw;   // 64 x 264 fp16 = 33.8 KB
        {
            int c = t & 63, k0 = (t >> 6) * 64;
            for (int k = k0; k < k0 + 64; ++k)
                Wt[c][k] = (_Float16)Wx[k * HID + c];
        }
        __syncthreads();
        int lane = t & 63, wv = t >> 6;
        int lg = lane >> 4, ln = lane & 15;
        int gb = bid - nbin - 3;
        int wid = gb * 4 + wv;
        int nw = ngemm * 4;
        float bb[4];
        #pragma unroll
        for (int g = 0; g < 4; ++g) bb[g] = bx[g * 16 + ln];
        int ntiles = N >> 4;
        for (int tile = wid; tile < ntiles; tile += nw) {
            int row0 = tile << 4;
            const float* xr = x + (size_t)(row0 + ln) * NFEAT + lg * 8;
            float4 av[16];
            #pragma unroll
            for (int ks = 0; ks < 8; ++ks) {
                av[2 * ks]     = *(const float4*)(xr + ks * 32);
                av[2 * ks + 1] = *(const float4*)(xr + ks * 32 + 4);
            }
            floatx4 acc[4] = {{0.f,0.f,0.f,0.f},{0.f,0.f,0.f,0.f},{0.f,0.f,0.f,0.f},{0.f,0.f,0.f,0.f}};
            #pragma unroll
            for (int ks = 0; ks < 8; ++ks) {
                float4 a0 = av[2 * ks], a1 = av[2 * ks + 1];
                half8 a;
                a[0]=(_Float16)a0.x; a[1]=(_Float16)a0.y; a[2]=(_Float16)a0.z; a[3]=(_Float16)a0.w;
                a[4]=(_Float16)a1.x; a[5]=(_Float16)a1.y; a[6]=(_Float16)a1.z; a[7]=(_Float16)a1.w;
                #pragma unroll
                for (int g = 0; g < 4; ++g) {
                    half8 b = *(const half8*)&Wt[g * 16 + ln][ks * 32 + lg * 8];
                    acc[g] = __builtin_amdgcn_mfma_f32_16x16x32_f16(a, b, acc[g], 0, 0, 0);
                }
            }
            #pragma unroll
            for (int g = 0; g < 4; ++g) {
                #pragma unroll
                for (int r = 0; r < 4; ++r) {
                    int row = row0 + lg * 4 + r;
                    h0[(size_t)row * HID + g * 16 + ln] = (_Float16)fmaxf(acc[g][r] + bb[g], 0.f);
                }
            }
        }
        return;
    }

    // ---- binning part ----
    BinSM* sm = (BinSM*)smraw;
    int base = bid * EPB;
    int n = E - base; if (n > EPB) n = EPB;
    sm->lcnt[t] = 0;
    __syncthreads();
    for (int i = t; i < n; i += 256) {
        int d = dst[base + i];
        sm->sdst[i] = d;
        atomicAdd(&sm->lcnt[d >> 9], 1);
    }
    __syncthreads();
    int v = sm->lcnt[t];
    int incl = block_iscan<256>(v, t, sm->wsum);
    int excl = incl - v;
    sm->loff[t] = excl; sm->lcur[t] = excl;
    __syncthreads();
    for (int i = t; i < n; i += 256) {
        int d = sm->sdst[i], s = src[base + i];
        int b = d >> 9;
        int p = atomicAdd(&sm->lcur[b], 1);
        sm->words[p] = s | ((d & 511) << 17);     // s < 2^17
    }
    __syncthreads();
    if (t < nbuckets) {
        int c = sm->lcnt[t];
        sm->gbase[t] = c > 0 ? atomicAdd(&bcur[t], c) : 0;
    }
    __syncthreads();
    int lane = t & 63, wv = t >> 6;
    for (int b = wv; b < nbuckets; b += 4) {
        int o = sm->loff[b], c = sm->lcnt[b], gb = sm->gbase[b];
        int* dstp = bwords + (size_t)b * BCAP;
        for (int i = lane; i < c; i += 64) {
            int gp = gb + i;
            if (gp < BCAP) dstp[gp] = sm->words[o + i];
        }
    }
}

// ---------- phase 2: per-bucket CSR build + pk/dinv ----------
__global__ __launch_bounds__(256) void k_csr(const int* __restrict__ bcur, const int* __restrict__ bwords,
                                             int* __restrict__ csr, unsigned* __restrict__ pk,
                                             float* __restrict__ dinv, int N) {
    __shared__ int cnt[512], cur[512], wsum[4];
    __shared__ int lcsr[BCAP];     // 32 KB
    int t = threadIdx.x;
    int b = blockIdx.x;
    int nodebase = b << 9;
    int nb = bcur[b]; if (nb > BCAP) nb = BCAP;
    cnt[t] = 0; cnt[t + 256] = 0;
    __syncthreads();
    const int* wp = bwords + (size_t)b * BCAP;
    for (int i = t; i < nb; i += 256)
        atomicAdd(&cnt[wp[i] >> 17], 1);
    __syncthreads();
    int v0 = cnt[2 * t], v1 = cnt[2 * t + 1];
    int p = v0 + v1;
    int incl = block_iscan<256>(p, t, wsum);
    int e = incl - p;
    cur[2 * t] = e; cur[2 * t + 1] = e + v0;
    #pragma unroll
    for (int j = 0; j < 2; ++j) {
        int node = nodebase + 2 * t + j;
        if (node < N) {
            int c = cnt[2 * t + j]; if (c > 2047) c = 2047;
            pk[node] = (unsigned)(b * BCAP + cur[2 * t + j]) | ((unsigned)c << 21);
            dinv[node] = rsqrtf((float)c + 1.0f);
        }
    }
    __syncthreads();
    for (int i = t; i < nb; i += 256) {
        int w = wp[i];
        int pos = atomicAdd(&cur[w >> 17], 1);
        lcsr[pos] = w & 0x1FFFF;
    }
    __syncthreads();
    int* cp = csr + (size_t)b * BCAP;
    for (int i = t; i < nb; i += 256) cp[i] = lcsr[i];
}

// ---------- fused GCN layer: z = A·h (gather+self), then out = z@W + b via MFMA ----------
// block = 256 thr = 4 waves = 32 nodes; wave = 8 subgroups x 8 lanes (sg owns node, f8 owns
// 16B feature seg). VGPR gathers (8 rows/chunk in flight); next chunk's csr/norm prefetched
// during consume to hide the serial csr->norm chain. WRN=1: compute+cache norm; WRN=0: load it.
// NOTE: this structure is the measured local optimum (R4); 5 restructures all regressed.
template<int WRN>
__global__ __launch_bounds__(256) void k_layer(const _Float16* __restrict__ Ph, const int* __restrict__ csr,
                                               const unsigned* __restrict__ pk, const float* __restrict__ dinv,
                                               const _Float16* __restrict__ Wt, const float* __restrict__ b,
                                               float* __restrict__ normf,
                                               _Float16* __restrict__ Lout, int N) {
    __shared__ _Float16 z[32][72];     // aggregated features
    __shared__ _Float16 ot[32][72];    // output tile
    int t = threadIdx.x;
    int lane = t & 63, wv = t >> 6;
    int sg = lane >> 3, f8 = lane & 7;
    int lg = lane >> 4, ln = lane & 15;
    int nb = blockIdx.x << 5;
    int node = nb + wv * 8 + sg;
    bool valid = node < N;
    int nodec = valid ? node : (N - 1);
    // B fragment from pre-converted fp16 W^T: 2 x half8 loads
    int col = wv * 16 + ln;
    half8 bf0 = *(const half8*)(Wt + col * 64 + lg * 8);
    half8 bf1 = *(const half8*)(Wt + col * 64 + 32 + lg * 8);
    float bb = b[col];

    unsigned pkv = valid ? pk[node] : 0u;
    int off = (int)(pkv & 0x1FFFFFu);
    int c = valid ? (int)(pkv >> 21) : 0;
    float dd = valid ? dinv[node] : 0.f;
    const _Float16* pb = Ph + f8 * 8;
    float acc[8];
    {
        half8 self = *(const half8*)(pb + (size_t)nodec * HID);
        float dd2 = dd * dd;
        #pragma unroll
        for (int j = 0; j < 8; ++j) acc[j] = (float)self[j] * dd2;
    }
    // prologue: chunk 0's edge data
    int ecur = f8;
    bool ok = ecur < c;
    int s_cur = ok ? csr[off + ecur] : nodec;
    float nm_cur;
    if (WRN) {
        nm_cur = ok ? dinv[s_cur] * dd : 0.f;
        if (ok) normf[off + ecur] = nm_cur;
    } else {
        nm_cur = ok ? normf[off + ecur] : 0.f;
    }
    for (int jj = 0; jj < c; jj += 8) {
        // prefetch next chunk's csr/norm (latency hidden under consume below)
        int en = jj + 8 + f8;
        bool okn = en < c;
        int s_nxt = okn ? csr[off + en] : nodec;
        float nm_nxt;
        if (WRN) {
            nm_nxt = okn ? dinv[s_nxt] * dd : 0.f;
            if (okn) normf[off + en] = nm_nxt;
        } else {
            nm_nxt = okn ? normf[off + en] : 0.f;
        }
        // consume current chunk: 8 broadcast rows
        #pragma unroll
        for (int j = 0; j < 8; ++j) {
            int ss = __shfl(s_cur, j, 8);
            float nn = __shfl(nm_cur, j, 8);
            half8 v = *(const half8*)(pb + (size_t)ss * HID);
            #pragma unroll
            for (int q = 0; q < 8; ++q) acc[q] = fmaf((float)v[q], nn, acc[q]);
        }
        s_cur = s_nxt; nm_cur = nm_nxt;
    }
    {
        half8 zv;
        #pragma unroll
        for (int j = 0; j < 8; ++j) zv[j] = (_Float16)acc[j];
        *(half8*)&z[wv * 8 + sg][f8 * 8] = zv;
    }
    __syncthreads();
    // MFMA: two 16-row tiles; out[rows][wv*16 .. wv*16+15] = z @ W
    floatx4 acc0 = {0.f, 0.f, 0.f, 0.f}, acc1 = {0.f, 0.f, 0.f, 0.f};
    {
        half8 a0 = *(const half8*)&z[ln][lg * 8];
        half8 a1 = *(const half8*)&z[16 + ln][lg * 8];
        acc0 = __builtin_amdgcn_mfma_f32_16x16x32_f16(a0, bf0, acc0, 0, 0, 0);
        acc1 = __builtin_amdgcn_mfma_f32_16x16x32_f16(a1, bf0, acc1, 0, 0, 0);
        a0 = *(const half8*)&z[ln][32 + lg * 8];
        a1 = *(const half8*)&z[16 + ln][32 + lg * 8];
        acc0 = __builtin_amdgcn_mfma_f32_16x16x32_f16(a0, bf1, acc0, 0, 0, 0);
        acc1 = __builtin_amdgcn_mfma_f32_16x16x32_f16(a1, bf1, acc1, 0, 0, 0);
    }
    #pragma unroll
    for (int r = 0; r < 4; ++r) {
        ot[lg * 4 + r][wv * 16 + ln] = (_Float16)(acc0[r] + bb);
        ot[16 + lg * 4 + r][wv * 16 + ln] = (_Float16)(acc1[r] + bb);
    }
    __syncthreads();
    // coalesced store of the 32x64 fp16 tile
    {
        int row = t >> 3, c8 = t & 7;
        int onode = nb + row;
        if (onode < N)
            *(half8*)(Lout + (size_t)onode * HID + c8 * 8) = *(const half8*)&ot[row][c8 * 8];
    }
}

// ---------- out = relu(((L1+L2+L3)/3) @ Wz + bz) ----------
__global__ __launch_bounds__(256) void k_gemm_out(const _Float16* __restrict__ L1, const _Float16* __restrict__ L2,
                                                  const _Float16* __restrict__ L3, const float* __restrict__ Wz,
                                                  const float* __restrict__ bz, float* __restrict__ outp, int N) {
    int t = threadIdx.x;
    int lane = t & 63, lg = lane >> 4, ln = lane & 15;
    int wid = (blockIdx.x * 256 + t) >> 6;
    int nw = (gridDim.x * 256) >> 6;
    half8 b[2][3];
    float bb[3];
    #pragma unroll
    for (int g = 0; g < 3; ++g) {
        int col = g * 16 + ln;
        bb[g] = (col < NCLASS) ? bz[col] : 0.f;
        #pragma unroll
        for (int ks = 0; ks < 2; ++ks)
            #pragma unroll
            for (int j = 0; j < 8; ++j)
                b[ks][g][j] = (col < NCLASS) ? (_Float16)(Wz[(ks * 32 + lg * 8 + j) * NCLASS + col] * (1.f / 3.f)) : (_Float16)0.f;
    }
    int ntiles = N >> 4;
    for (int tile = wid; tile < ntiles; tile += nw) {
        int row0 = tile << 4;
        size_t rb = (size_t)(row0 + ln) * HID + lg * 8;
        floatx4 acc[3] = {{0.f,0.f,0.f,0.f},{0.f,0.f,0.f,0.f},{0.f,0.f,0.f,0.f}};
        #pragma unroll
        for (int ks = 0; ks < 2; ++ks) {
            half8 a1 = *(const half8*)(L1 + rb + ks * 32);
            half8 a2 = *(const half8*)(L2 + rb + ks * 32);
            half8 a3 = *(const half8*)(L3 + rb + ks * 32);
            half8 a;
            #pragma unroll
            for (int j = 0; j < 8; ++j)
                a[j] = (_Float16)((float)a1[j] + (float)a2[j] + (float)a3[j]);
            #pragma unroll
            for (int g = 0; g < 3; ++g)
                acc[g] = __builtin_amdgcn_mfma_f32_16x16x32_f16(a, b[ks][g], acc[g], 0, 0, 0);
        }
        #pragma unroll
        for (int g = 0; g < 3; ++g) {
            int col = g * 16 + ln;
            if (col < NCLASS) {
                #pragma unroll
                for (int r = 0; r < 4; ++r)
                    outp[(size_t)(row0 + lg * 4 + r) * NCLASS + col] = fmaxf(acc[g][r] + bb[g], 0.f);
            }
        }
    }
}

extern "C" void kernel_launch(void* const* d_in, const int* in_sizes, int n_in,
                              void* d_out, int out_size, void* d_ws, size_t ws_size,
                              hipStream_t stream) {
    const float* x  = (const float*)d_in[0];
    const int*   ei = (const int*)d_in[1];
    const float* Wx = (const float*)d_in[2];
    const float* bx = (const float*)d_in[3];
    const float* W1 = (const float*)d_in[4];
    const float* b1 = (const float*)d_in[5];
    const float* W2 = (const float*)d_in[6];
    const float* b2 = (const float*)d_in[7];
    const float* W3 = (const float*)d_in[8];
    const float* b3 = (const float*)d_in[9];
    const float* Wz = (const float*)d_in[10];
    const float* bz = (const float*)d_in[11];
    float* out = (float*)d_out;

    int N = in_sizes[0] / NFEAT;
    int E = in_sizes[1] / 2;
    const int* src = ei;
    const int* dst = ei + E;
    int nbuckets = (N + 511) >> 9;   // 196 for N=100000 (<=256)

    size_t nh = (size_t)N * HID;
    size_t Npad = ((size_t)N + 7) / 8 * 8;
    // 4B-unit layout: bcur[256] | dinv | pk | H0 | L1 | L2 | L3 | bwords | csr | Wt16 | normf
    int*      bcur = (int*)d_ws;
    float*    dinv = (float*)d_ws + 256;
    unsigned* pk   = (unsigned*)(dinv + Npad);
    _Float16* H0   = (_Float16*)(pk + Npad);
    _Float16* L1   = H0 + nh;
    _Float16* L2   = L1 + nh;
    _Float16* L3   = L2 + nh;
    int*      bwords = (int*)(L3 + nh);
    int*      csr  = bwords + (size_t)nbuckets * BCAP;
    _Float16* Wt16 = (_Float16*)(csr + (size_t)nbuckets * BCAP);
    float*    normf = (float*)(Wt16 + 3 * 4096);

    int nbin = (E + EPB - 1) / EPB;   // 489 binning blocks at EPB=2048
    int ngemm = 512;
    hipMemsetAsync(bcur, 0, 256 * sizeof(int), stream);
    k_pre<<<nbin + 3 + ngemm, 256, 0, stream>>>(src, dst, bcur, bwords, nbuckets, E, nbin,
                                                W1, W2, W3, Wt16, x, Wx, bx, H0, N, ngemm);
    k_csr<<<nbuckets, 256, 0, stream>>>(bcur, bwords, csr, pk, dinv, N);

    int layer_blocks = (N + 31) / 32;
    k_layer<1><<<layer_blocks, 256, 0, stream>>>(H0, csr, pk, dinv, Wt16,          b1, normf, L1, N);
    k_layer<0><<<layer_blocks, 256, 0, stream>>>(L1, csr, pk, dinv, Wt16 + 4096,   b2, normf, L2, N);
    k_layer<0><<<layer_blocks, 256, 0, stream>>>(L2, csr, pk, dinv, Wt16 + 8192,   b3, normf, L3, N);

    k_gemm_out<<<512, 256, 0, stream>>>(L1, L2, L3, Wz, bz, out, N);
}